// Round 1
// baseline (70.506 us; speedup 1.0000x reference)
//
#include <hip/hip_runtime.h>

using f32x4  = __attribute__((ext_vector_type(4))) float;
using bf16x8 = __attribute__((ext_vector_type(8))) short;

constexpr int N_ = 512;
constexpr int K_ = 512;
constexpr int BM = 128, BN = 128, BK = 64;
constexpr int LDSK = 72;   // bf16 elems per LDS row: 64 + 8 pad (breaks bank conflict)

__device__ inline ushort f2bf(float f) {
  union { float f; unsigned u; } a; a.f = f;
  unsigned u = a.u;
  return (ushort)((u + 0x7fffu + ((u >> 16) & 1u)) >> 16);  // round-to-nearest-even
}

__global__ __launch_bounds__(256, 2)
void gemm_bf16_kernel(const float* __restrict__ X, const float* __restrict__ W,
                      float* __restrict__ C) {
  __shared__ ushort As[BM * LDSK];
  __shared__ ushort Bs[BN * LDSK];

  const int t    = threadIdx.x;
  const int lane = t & 63;
  const int wave = t >> 6;
  const int wr   = wave >> 1;   // 0..1: wave row within block
  const int wc   = wave & 1;    // 0..1: wave col within block

  const int bid = blockIdx.x;
  const int bn  = bid & 3;      // 4 column tiles (N=512 / 128)
  const int bm  = bid >> 2;
  const int m0  = bm * BM;
  const int n0  = bn * BN;

  // staging: 256 threads cover 16 rows x 64 cols (f32x4 each) per iter
  const int sr = t >> 4;        // 0..15
  const int sc = (t & 15) * 4;  // 0,4,...,60

  f32x4 acc[4][4] = {};

  for (int ks = 0; ks < K_ / BK; ++ks) {
    const int k0 = ks * BK;
    if (ks) __syncthreads();

    // Stage A (activations) and B (weights), fp32 -> bf16, into padded LDS
#pragma unroll
    for (int i = 0; i < 8; ++i) {
      const int r = sr + i * 16;
      f32x4 va = *reinterpret_cast<const f32x4*>(&X[(size_t)(m0 + r) * K_ + (k0 + sc)]);
      f32x4 vb = *reinterpret_cast<const f32x4*>(&W[(size_t)(n0 + r) * K_ + (k0 + sc)]);
      ushort4 ha, hb;
      ha.x = f2bf(va.x); ha.y = f2bf(va.y); ha.z = f2bf(va.z); ha.w = f2bf(va.w);
      hb.x = f2bf(vb.x); hb.y = f2bf(vb.y); hb.z = f2bf(vb.z); hb.w = f2bf(vb.w);
      *reinterpret_cast<ushort4*>(&As[r * LDSK + sc]) = ha;
      *reinterpret_cast<ushort4*>(&Bs[r * LDSK + sc]) = hb;
    }
    __syncthreads();

#pragma unroll
    for (int kk = 0; kk < 2; ++kk) {
      const int kof = kk * 32 + (lane >> 4) * 8;
      bf16x8 a[4], b[4];
#pragma unroll
      for (int mi = 0; mi < 4; ++mi)
        a[mi] = *reinterpret_cast<const bf16x8*>(
            &As[(wr * 64 + mi * 16 + (lane & 15)) * LDSK + kof]);
#pragma unroll
      for (int ni = 0; ni < 4; ++ni)
        b[ni] = *reinterpret_cast<const bf16x8*>(
            &Bs[(wc * 64 + ni * 16 + (lane & 15)) * LDSK + kof]);
#pragma unroll
      for (int mi = 0; mi < 4; ++mi)
#pragma unroll
        for (int ni = 0; ni < 4; ++ni)
          acc[mi][ni] = __builtin_amdgcn_mfma_f32_16x16x32_bf16(a[mi], b[ni],
                                                                acc[mi][ni], 0, 0, 0);
    }
  }

  // Epilogue: C/D layout col = lane&15, row = (lane>>4)*4 + reg
  const int ccol0 = n0 + wc * 64 + (lane & 15);
  const int rsub  = (lane >> 4) * 4;
#pragma unroll
  for (int mi = 0; mi < 4; ++mi) {
#pragma unroll
    for (int ni = 0; ni < 4; ++ni) {
#pragma unroll
      for (int r = 0; r < 4; ++r) {
        C[(size_t)(m0 + wr * 64 + mi * 16 + rsub + r) * N_ + (ccol0 + ni * 16)] =
            acc[mi][ni][r];
      }
    }
  }
}

extern "C" void kernel_launch(void* const* d_in, const int* in_sizes, int n_in,
                              void* d_out, int out_size, void* d_ws, size_t ws_size,
                              hipStream_t stream) {
  const float* x = (const float*)d_in[0];
  const float* w = (const float*)d_in[1];
  float* out = (float*)d_out;
  const int M = in_sizes[0] / K_;            // 4*8192 = 32768
  dim3 grid((M / BM) * (N_ / BN));           // 256 * 4 = 1024 blocks
  gemm_bf16_kernel<<<grid, dim3(256), 0, stream>>>(x, w, out);
}

// Round 2
// 39.508 us; speedup vs baseline: 1.7846x; 1.7846x over previous
//
#include <hip/hip_runtime.h>
#include <hip/hip_bf16.h>

using f32x4  = __attribute__((ext_vector_type(4))) float;
using bf16x8 = __attribute__((ext_vector_type(8))) short;

constexpr int N_ = 512;
constexpr int K_ = 512;
constexpr int BM = 128, BN = 128, BK = 64;
constexpr int LDSK = 72;   // 64 + 8 pad
constexpr int NKS = K_ / BK;  // 8

__device__ inline ushort f2bf(float f) {
  union { __hip_bfloat16 h; ushort u; } c;
  c.h = __float2bfloat16(f);
  return c.u;
}

__global__ __launch_bounds__(512, 4)
void gemm_bf16_kernel(const float* __restrict__ X, const float* __restrict__ W,
                      float* __restrict__ C) {
  __shared__ ushort As[BM * LDSK];
  __shared__ ushort Bs[BN * LDSK];

  const int t    = threadIdx.x;
  const int lane = t & 63;
  const int wave = t >> 6;      // 0..7
  const int wr   = wave >> 2;   // 0..1 -> 64-row slab
  const int wc   = wave & 3;    // 0..3 -> 32-col slab

  // XCD-aware bijective swizzle: 1024 blocks, 8 XCDs, 128 logical tiles each.
  // Consecutive logical tiles share bm -> x row-panel stays hot in that XCD's L2.
  const int nwg = gridDim.x;
  const int cpx = nwg >> 3;
  const int bid = (blockIdx.x & 7) * cpx + (blockIdx.x >> 3);
  const int bn  = bid & 3;
  const int bm  = bid >> 2;
  const int m0 = bm * BM, n0 = bn * BN;

  // staging map: 512 threads cover 32 rows x 64 cols (f32x4) per slab
  const int sr = t >> 4;        // 0..31
  const int sc = (t & 15) * 4;  // 0,4,...,60

  const float* xp = X + (size_t)(m0 + sr) * K_ + sc;
  const float* wp = W + (size_t)(n0 + sr) * K_ + sc;

  f32x4 acc[4][2] = {};
  f32x4 ra[4], rb[4];

  // ---- prologue: load + stage K-step 0 ----
#pragma unroll
  for (int i = 0; i < 4; ++i) {
    ra[i] = *reinterpret_cast<const f32x4*>(xp + (size_t)(i * 32) * K_);
    rb[i] = *reinterpret_cast<const f32x4*>(wp + (size_t)(i * 32) * K_);
  }
#pragma unroll
  for (int i = 0; i < 4; ++i) {
    ushort4 ha, hb;
    ha.x = f2bf(ra[i].x); ha.y = f2bf(ra[i].y); ha.z = f2bf(ra[i].z); ha.w = f2bf(ra[i].w);
    hb.x = f2bf(rb[i].x); hb.y = f2bf(rb[i].y); hb.z = f2bf(rb[i].z); hb.w = f2bf(rb[i].w);
    *reinterpret_cast<ushort4*>(&As[(sr + 32 * i) * LDSK + sc]) = ha;
    *reinterpret_cast<ushort4*>(&Bs[(sr + 32 * i) * LDSK + sc]) = hb;
  }
  __syncthreads();

  for (int ks = 1; ks < NKS; ++ks) {
    // 1) issue global loads for step ks (latency hides under MFMA below)
#pragma unroll
    for (int i = 0; i < 4; ++i) {
      ra[i] = *reinterpret_cast<const f32x4*>(xp + (size_t)(i * 32) * K_ + ks * BK);
      rb[i] = *reinterpret_cast<const f32x4*>(wp + (size_t)(i * 32) * K_ + ks * BK);
    }

    // 2) MFMA on step ks-1 (currently in LDS)
#pragma unroll
    for (int kk = 0; kk < 2; ++kk) {
      const int kof = kk * 32 + (lane >> 4) * 8;
      bf16x8 a[4], b[2];
#pragma unroll
      for (int mi = 0; mi < 4; ++mi)
        a[mi] = *reinterpret_cast<const bf16x8*>(
            &As[(wr * 64 + mi * 16 + (lane & 15)) * LDSK + kof]);
#pragma unroll
      for (int ni = 0; ni < 2; ++ni)
        b[ni] = *reinterpret_cast<const bf16x8*>(
            &Bs[(wc * 32 + ni * 16 + (lane & 15)) * LDSK + kof]);
#pragma unroll
      for (int mi = 0; mi < 4; ++mi)
#pragma unroll
        for (int ni = 0; ni < 2; ++ni)
          acc[mi][ni] = __builtin_amdgcn_mfma_f32_16x16x32_bf16(a[mi], b[ni],
                                                                acc[mi][ni], 0, 0, 0);
    }
    __syncthreads();   // readers of step ks-1 done

    // 3) convert + write step ks to LDS
#pragma unroll
    for (int i = 0; i < 4; ++i) {
      ushort4 ha, hb;
      ha.x = f2bf(ra[i].x); ha.y = f2bf(ra[i].y); ha.z = f2bf(ra[i].z); ha.w = f2bf(ra[i].w);
      hb.x = f2bf(rb[i].x); hb.y = f2bf(rb[i].y); hb.z = f2bf(rb[i].z); hb.w = f2bf(rb[i].w);
      *reinterpret_cast<ushort4*>(&As[(sr + 32 * i) * LDSK + sc]) = ha;
      *reinterpret_cast<ushort4*>(&Bs[(sr + 32 * i) * LDSK + sc]) = hb;
    }
    __syncthreads();
  }

  // ---- epilogue MFMA on last staged step ----
#pragma unroll
  for (int kk = 0; kk < 2; ++kk) {
    const int kof = kk * 32 + (lane >> 4) * 8;
    bf16x8 a[4], b[2];
#pragma unroll
    for (int mi = 0; mi < 4; ++mi)
      a[mi] = *reinterpret_cast<const bf16x8*>(
          &As[(wr * 64 + mi * 16 + (lane & 15)) * LDSK + kof]);
#pragma unroll
    for (int ni = 0; ni < 2; ++ni)
      b[ni] = *reinterpret_cast<const bf16x8*>(
          &Bs[(wc * 32 + ni * 16 + (lane & 15)) * LDSK + kof]);
#pragma unroll
    for (int mi = 0; mi < 4; ++mi)
#pragma unroll
      for (int ni = 0; ni < 2; ++ni)
        acc[mi][ni] = __builtin_amdgcn_mfma_f32_16x16x32_bf16(a[mi], b[ni],
                                                              acc[mi][ni], 0, 0, 0);
  }

  // ---- store: C/D layout col = lane&15, row = (lane>>4)*4 + reg ----
  const int col0 = n0 + wc * 32 + (lane & 15);
  const int rsub = (lane >> 4) * 4;
#pragma unroll
  for (int mi = 0; mi < 4; ++mi)
#pragma unroll
    for (int ni = 0; ni < 2; ++ni)
#pragma unroll
      for (int r = 0; r < 4; ++r)
        C[(size_t)(m0 + wr * 64 + mi * 16 + rsub + r) * N_ + (col0 + ni * 16)] =
            acc[mi][ni][r];
}

extern "C" void kernel_launch(void* const* d_in, const int* in_sizes, int n_in,
                              void* d_out, int out_size, void* d_ws, size_t ws_size,
                              hipStream_t stream) {
  const float* x = (const float*)d_in[0];
  const float* w = (const float*)d_in[1];
  float* out = (float*)d_out;
  const int M = in_sizes[0] / K_;            // 32768
  dim3 grid((M / BM) * (N_ / BN));           // 1024 blocks
  gemm_bf16_kernel<<<grid, dim3(512), 0, stream>>>(x, w, out);
}

// Round 3
// 37.530 us; speedup vs baseline: 1.8786x; 1.0527x over previous
//
#include <hip/hip_runtime.h>
#include <hip/hip_bf16.h>

using f32x4  = __attribute__((ext_vector_type(4))) float;
using bf16x8 = __attribute__((ext_vector_type(8))) short;

constexpr int N_ = 512;
constexpr int K_ = 512;
constexpr int BM = 128, BN = 128, BK = 64;
constexpr int LDSK = 72;      // 64 + 8 pad
constexpr int NKS = K_ / BK;  // 8

__device__ inline ushort f2bf(float f) {
  union { __hip_bfloat16 h; ushort u; } c;
  c.h = __float2bfloat16(f);
  return c.u;
}

__global__ __launch_bounds__(512, 4)
void gemm_bf16_kernel(const float* __restrict__ X, const float* __restrict__ W,
                      float* __restrict__ C) {
  __shared__ ushort As[2][BM * LDSK];
  __shared__ ushort Bs[2][BN * LDSK];

  const int t    = threadIdx.x;
  const int lane = t & 63;
  const int wave = t >> 6;      // 0..7
  const int wr   = wave >> 2;   // 0..1 -> 64-row slab
  const int wc   = wave & 3;    // 0..3 -> 32-col slab

  // XCD-aware bijective swizzle (1024 blocks = 8 XCDs x 128): the 4 bn-tiles
  // of each x row-panel land on the same XCD -> x re-reads are L2/L3 hits.
  const int cpx = gridDim.x >> 3;
  const int bid = (blockIdx.x & 7) * cpx + (blockIdx.x >> 3);
  const int bn  = bid & 3;
  const int bm  = bid >> 2;
  const int m0 = bm * BM, n0 = bn * BN;

  // staging map: 512 threads cover 32 rows x 64 cols (f32x4) per slab
  const int sr = t >> 4;        // 0..31
  const int sc = (t & 15) * 4;  // 0,4,...,60

  const float* xp = X + (size_t)(m0 + sr) * K_ + sc;
  const float* wp = W + (size_t)(n0 + sr) * K_ + sc;

  f32x4 acc[4][2] = {};
  f32x4 ra[2][4], rb[2][4];

  auto LOAD = [&](int set, int ks) {
#pragma unroll
    for (int i = 0; i < 4; ++i) {
      ra[set][i] = *reinterpret_cast<const f32x4*>(xp + (size_t)(i * 32) * K_ + ks * BK);
      rb[set][i] = *reinterpret_cast<const f32x4*>(wp + (size_t)(i * 32) * K_ + ks * BK);
    }
  };

  auto STAGE = [&](int set, int buf) {   // cvt fp32->bf16 + LDS write (waits vmcnt)
#pragma unroll
    for (int i = 0; i < 4; ++i) {
      ushort4 ha, hb;
      ha.x = f2bf(ra[set][i].x); ha.y = f2bf(ra[set][i].y);
      ha.z = f2bf(ra[set][i].z); ha.w = f2bf(ra[set][i].w);
      hb.x = f2bf(rb[set][i].x); hb.y = f2bf(rb[set][i].y);
      hb.z = f2bf(rb[set][i].z); hb.w = f2bf(rb[set][i].w);
      *reinterpret_cast<ushort4*>(&As[buf][(sr + 32 * i) * LDSK + sc]) = ha;
      *reinterpret_cast<ushort4*>(&Bs[buf][(sr + 32 * i) * LDSK + sc]) = hb;
    }
  };

  auto MMA = [&](int buf) {
#pragma unroll
    for (int kk = 0; kk < 2; ++kk) {
      const int kof = kk * 32 + (lane >> 4) * 8;
      bf16x8 a[4], b[2];
#pragma unroll
      for (int mi = 0; mi < 4; ++mi)
        a[mi] = *reinterpret_cast<const bf16x8*>(
            &As[buf][(wr * 64 + mi * 16 + (lane & 15)) * LDSK + kof]);
#pragma unroll
      for (int ni = 0; ni < 2; ++ni)
        b[ni] = *reinterpret_cast<const bf16x8*>(
            &Bs[buf][(wc * 32 + ni * 16 + (lane & 15)) * LDSK + kof]);
#pragma unroll
      for (int mi = 0; mi < 4; ++mi)
#pragma unroll
        for (int ni = 0; ni < 2; ++ni)
          acc[mi][ni] = __builtin_amdgcn_mfma_f32_16x16x32_bf16(a[mi], b[ni],
                                                                acc[mi][ni], 0, 0, 0);
    }
  };

  // ---- prologue: loads for ks=0,1 in flight; stage ks=0 into buf0 ----
  LOAD(0, 0);
  LOAD(1, 1);
  STAGE(0, 0);
  __syncthreads();

  // ---- main loop: 1 barrier per K-step; MFMA(buf cur) overlaps stage(buf other)
#pragma unroll
  for (int ks = 0; ks < NKS - 1; ++ks) {
    if (ks + 2 < NKS) LOAD(ks & 1, ks + 2);   // issue 2 steps ahead
    MMA(ks & 1);                               // compute current (no vm wait)
    STAGE((ks + 1) & 1, (ks + 1) & 1);         // waits loads issued 1 iter ago
    __syncthreads();
  }
  MMA((NKS - 1) & 1);

  // ---- store: C/D layout col = lane&15, row = (lane>>4)*4 + reg ----
  const int col0 = n0 + wc * 32 + (lane & 15);
  const int rsub = (lane >> 4) * 4;
#pragma unroll
  for (int mi = 0; mi < 4; ++mi)
#pragma unroll
    for (int ni = 0; ni < 2; ++ni)
#pragma unroll
      for (int r = 0; r < 4; ++r)
        C[(size_t)(m0 + wr * 64 + mi * 16 + rsub + r) * N_ + (col0 + ni * 16)] =
            acc[mi][ni][r];
}

extern "C" void kernel_launch(void* const* d_in, const int* in_sizes, int n_in,
                              void* d_out, int out_size, void* d_ws, size_t ws_size,
                              hipStream_t stream) {
  const float* x = (const float*)d_in[0];
  const float* w = (const float*)d_in[1];
  float* out = (float*)d_out;
  const int M = in_sizes[0] / K_;            // 32768
  dim3 grid((M / BM) * (N_ / BN));           // 1024 blocks
  gemm_bf16_kernel<<<grid, dim3(512), 0, stream>>>(x, w, out);
}